// Round 1
// baseline (614.169 us; speedup 1.0000x reference)
//
#include <hip/hip_runtime.h>
#include <stdint.h>

// Problem constants
#define B_  16
#define T_  2048
#define C_  200
#define D_  2048
#define K_  (B_*T_)          // 32768
#define CP  208              // C padded to 13*16 MFMA M-tiles
#define BN  64               // d-tile width per workgroup (4 waves x 16 cols)
#define BK  32               // K per MFMA step
#define KSPLIT 16
#define KCHUNK (K_/KSPLIT)   // 2048
#define NSTEPS (KCHUNK/BK)   // 64
#define ASTR 40              // LDS row stride (bf16 elems): 80B, 16B-aligned, breaks bank conflicts
#define BSTR 40

typedef short bf16x8 __attribute__((ext_vector_type(8)));
typedef float f32x4  __attribute__((ext_vector_type(4)));

// fp32 -> bf16 bits, round-to-nearest-even (inputs are finite normals)
__device__ __forceinline__ unsigned short f2bf(float f) {
    uint32_t u = __float_as_uint(f);
    u += 0x7FFFu + ((u >> 16) & 1u);
    return (unsigned short)(u >> 16);
}

// ---------------------------------------------------------------------------
// Kernel 1: build bf16 maskT[c][k] (c-major rows, k contiguous) + counts[c].
// mask[k=b*T+t][c] = (act[b,t,c]!=0) && (vid[b,c]!=0).  One WG per 128 k-rows
// (never straddles a batch b since 128 | T).  LDS transpose: contiguous int4
// reads of act, scattered LDS writes, coalesced 8B global writes of maskT.
// ---------------------------------------------------------------------------
__global__ __launch_bounds__(256) void mask_kernel(
    const int* __restrict__ act, const int* __restrict__ vid,
    unsigned short* __restrict__ maskT, int* __restrict__ counts) {
    __shared__ unsigned short Ms[C_][136];   // [200][128+8pad] bf16 bits
    __shared__ int vidL[C_];
    const int t  = threadIdx.x;
    const int k0 = blockIdx.x * 128;
    const int b  = k0 / T_;                  // constant per block
    if (t < C_) vidL[t] = vid[b*C_ + t];
    __syncthreads();

    // Phase 1: tile = act[k0*200 .. (k0+128)*200) is fully contiguous.
    const int4* actv = (const int4*)(act + (size_t)k0 * C_);
    #pragma unroll
    for (int j = 0; j < 25; ++j) {           // 256*25*4 = 25600 ints = 128*200
        int idx = t + 256*j;
        int4 a = actv[idx];
        int q = idx * 4;
        #pragma unroll
        for (int i = 0; i < 4; ++i) {
            int qq = q + i;
            int kl = qq / 200;               // compiler: magic-mul
            int c  = qq % 200;
            int av = (i==0) ? a.x : (i==1) ? a.y : (i==2) ? a.z : a.w;
            int bit = (av != 0) && (vidL[c] != 0);
            Ms[c][kl] = bit ? 0x3F80 : 0;    // bf16 1.0 or 0.0
        }
    }
    __syncthreads();

    // Phase 2a: coalesced maskT writes (rows c>=200 are zero padding).
    #pragma unroll
    for (int j = 0; j < 26; ++j) {           // 256*26 = 6656 = 208 rows * 32 chunks
        int idx = t + 256*j;
        int c  = idx >> 5;
        int ch = idx & 31;
        ushort4 v;
        if (c < C_) v = *(const ushort4*)&Ms[c][ch*4];
        else        v = make_ushort4(0,0,0,0);
        *(ushort4*)&maskT[(size_t)c*K_ + k0 + ch*4] = v;
    }
    // Phase 2b: per-class counts for this k-tile.
    if (t < C_) {
        int s = 0;
        #pragma unroll 8
        for (int k = 0; k < 128; ++k) s += (Ms[t][k] != 0);
        if (s) atomicAdd(&counts[t], s);
    }
}

// ---------------------------------------------------------------------------
// Kernel 2: sums[c][d] += maskT^T-GEMM.  A = mask (M=208 c-rows), B = feats
// (K x 64 d-cols, transposed into LDS as [d][k] for k-contiguous B-frags).
// mfma_f32_16x16x32_bf16; frag layouts: A[m=l&15][k=(l>>4)*8+j],
// B[k=(l>>4)*8+j][n=l&15], C/D col=l&15, row=(l>>4)*4+reg (HW-verified).
// Each WG owns one (d-tile, k-chunk); feats read exactly once grid-wide.
// ---------------------------------------------------------------------------
__global__ __launch_bounds__(256) void gemm_kernel(
    const float* __restrict__ feats, const unsigned short* __restrict__ maskT,
    float* __restrict__ sums) {
    __shared__ unsigned short As[CP][ASTR];  // [208][40]
    __shared__ unsigned short Bs[BN][BSTR];  // [64][40]
    const int t     = threadIdx.x;
    const int dt    = blockIdx.x & 31;       // 32 d-tiles
    const int ks    = blockIdx.x >> 5;       // 16 k-splits
    const int d0    = dt * BN;
    const int kbase = ks * KCHUNK;
    const int w     = t >> 6;
    const int lane  = t & 63;
    const int l15   = lane & 15;
    const int lg    = lane >> 4;

    f32x4 acc[13];
    #pragma unroll
    for (int m = 0; m < 13; ++m) acc[m] = (f32x4){0.f, 0.f, 0.f, 0.f};

    for (int s = 0; s < NSTEPS; ++s) {
        const int k0 = kbase + s * BK;
        __syncthreads();
        // Stage A: mask tile [208 c][32 k], 64B-contiguous per 16-thread group.
        #pragma unroll
        for (int j = 0; j < 13; ++j) {       // 256*13 = 3328 = 208*16 ushort2
            int idx = t + 256*j;
            int c  = idx >> 4;
            int kp = idx & 15;
            ushort2 v = *(const ushort2*)&maskT[(size_t)c*K_ + k0 + kp*2];
            *(ushort2*)&As[c][kp*2] = v;
        }
        // Stage B: feats tile [32 k][64 d] fp32, transpose to Bs[d][k] bf16.
        #pragma unroll
        for (int j = 0; j < 2; ++j) {        // 256*2 = 512 = 32*16 float4
            int idx = t + 256*j;
            int kk = idx >> 4;
            int d4 = idx & 15;
            float4 f = *(const float4*)&feats[(size_t)(k0+kk)*D_ + d0 + d4*4];
            Bs[d4*4+0][kk] = f2bf(f.x);
            Bs[d4*4+1][kk] = f2bf(f.y);
            Bs[d4*4+2][kk] = f2bf(f.z);
            Bs[d4*4+3][kk] = f2bf(f.w);
        }
        __syncthreads();
        bf16x8 bfrag = *(const bf16x8*)&Bs[w*16 + l15][lg*8];
        #pragma unroll
        for (int m = 0; m < 13; ++m) {
            bf16x8 afrag = *(const bf16x8*)&As[m*16 + l15][lg*8];
            acc[m] = __builtin_amdgcn_mfma_f32_16x16x32_bf16(afrag, bfrag, acc[m], 0, 0, 0);
        }
    }

    // Split-K reduce via fp32 atomics (sums zeroed by memset).
    const int d = d0 + w*16 + l15;
    #pragma unroll
    for (int m = 0; m < 13; ++m) {
        #pragma unroll
        for (int r = 0; r < 4; ++r) {
            int c = m*16 + lg*4 + r;
            atomicAdd(&sums[c*D_ + d], acc[m][r]);
        }
    }
}

// ---------------------------------------------------------------------------
// Kernel 3: out = counts>0 ? (1-m)*proto + m*(sums/counts) : proto
// ---------------------------------------------------------------------------
__global__ __launch_bounds__(256) void epi_kernel(
    const float* __restrict__ proto, const float* __restrict__ sums,
    const int* __restrict__ counts, float* __restrict__ out) {
    int i4 = blockIdx.x*256 + threadIdx.x;   // < 102400 float4s
    int c  = i4 >> 9;                        // 512 float4 per class row
    float4 p = *(const float4*)&proto[(size_t)i4*4];
    float4 s = *(const float4*)&sums[(size_t)i4*4];
    int cnt = counts[c];
    float4 o;
    if (cnt > 0) {
        float inv = 0.001f / (float)cnt;     // m / counts  (counts>0 so max(,1)=cnt)
        const float om = 1.0f - 0.001f;
        o.x = om*p.x + s.x*inv;
        o.y = om*p.y + s.y*inv;
        o.z = om*p.z + s.z*inv;
        o.w = om*p.w + s.w*inv;
    } else {
        o = p;
    }
    *(float4*)&out[(size_t)i4*4] = o;
}

extern "C" void kernel_launch(void* const* d_in, const int* in_sizes, int n_in,
                              void* d_out, int out_size, void* d_ws, size_t ws_size,
                              hipStream_t stream) {
    const float* feats = (const float*)d_in[0];
    const int*   act   = (const int*)d_in[1];
    const int*   vid   = (const int*)d_in[2];
    const float* proto = (const float*)d_in[3];
    float* out = (float*)d_out;

    // ws layout: [counts: 1024B][sums: CP*D*4 = 1,703,936B][maskT: CP*K*2 = 13,631,488B]
    char* ws = (char*)d_ws;
    int*            counts = (int*)ws;
    float*          sums   = (float*)(ws + 1024);
    unsigned short* maskT  = (unsigned short*)(ws + 1024 + (size_t)CP*D_*4);

    hipMemsetAsync(ws, 0, 1024 + (size_t)CP*D_*4, stream);  // zero counts + sums
    mask_kernel<<<K_/128, 256, 0, stream>>>(act, vid, maskT, counts);
    gemm_kernel<<<32*KSPLIT, 256, 0, stream>>>(feats, maskT, sums);
    epi_kernel<<<(C_*D_/4)/256, 256, 0, stream>>>(proto, sums, counts, out);
}